// Round 21
// baseline (96.279 us; speedup 1.0000x reference)
//
#include <hip/hip_runtime.h>

#define B_  4
#define S_  1024
#define D_  1024
#define H_  16
#define DK_ 64

typedef __attribute__((ext_vector_type(8)))  short bf16x8;
typedef __attribute__((ext_vector_type(4)))  short bf16x4;
typedef __attribute__((ext_vector_type(4)))  float f32x4;
typedef __attribute__((ext_vector_type(16))) float f32x16;

static __device__ __forceinline__ unsigned short f2bf(float f) {
  union { float f; unsigned u; } v; v.f = f;
  unsigned r = v.u + 0x7FFFu + ((v.u >> 16) & 1u);   // RNE
  return (unsigned short)(r >> 16);
}

static __device__ __forceinline__ unsigned cvtpk(float lo, float hi) {
  unsigned r;
  asm("v_cvt_pk_bf16_f32 %0, %1, %2" : "=v"(r) : "v"(lo), "v"(hi));
  return r;
}
static __device__ __forceinline__ void plswap(unsigned &a, unsigned &b) {
  asm volatile("v_permlane32_swap_b32 %0, %1" : "+v"(a), "+v"(b));
}

typedef __attribute__((address_space(1))) const void gc_t;
typedef __attribute__((address_space(3))) void lds_t;
static __device__ __forceinline__ void gload_lds16(const void* g, void* l) {
  __builtin_amdgcn_global_load_lds((gc_t*)g, (lds_t*)l, 16, 0, 0);
}

#define TM_ (1u << 22)
#define WM_ (1u << 20)

// -0.125 * log2(e): sigmoid(0.125*t) = 1/(1+exp2(CEXP*t)); folded into Wq.
#define CEXP_ (-0.18033688011112042f)

// ---------------------------------------------------------------------------
// cvt_w: weights for proj only (segs 0-2): seg0=CEXP*Wq, seg1=Wk0+0.5*Wk1,
// seg2=Wv.  1536 blocks.  (Wo/seg3 is converted inside proj's tail blocks.)
// ---------------------------------------------------------------------------
__global__ __launch_bounds__(256)
void cvt_w(const float* __restrict__ w0, const float* __restrict__ w1,
           const float* __restrict__ w2, const float* __restrict__ w3,
           unsigned short* __restrict__ wbf)
{
  const size_t u = ((size_t)blockIdx.x * 256 + threadIdx.x) * 8;
  const int seg = (int)(u >> 20);
  const size_t off = u & (WM_ - 1);
  unsigned short t[8];
  if (seg == 1) {               // W' = Wk0 + 0.5*Wk1 (f32, round once)
    float4 a0 = *(const float4*)(w1 + off);
    float4 a1 = *(const float4*)(w1 + off + 4);
    float4 b0 = *(const float4*)(w2 + off);
    float4 b1 = *(const float4*)(w2 + off + 4);
    t[0]=f2bf(a0.x+0.5f*b0.x); t[1]=f2bf(a0.y+0.5f*b0.y);
    t[2]=f2bf(a0.z+0.5f*b0.z); t[3]=f2bf(a0.w+0.5f*b0.w);
    t[4]=f2bf(a1.x+0.5f*b1.x); t[5]=f2bf(a1.y+0.5f*b1.y);
    t[6]=f2bf(a1.z+0.5f*b1.z); t[7]=f2bf(a1.w+0.5f*b1.w);
  } else {
    const float sc = (seg == 0) ? CEXP_ : 1.0f;
    const float* src = (seg == 0) ? w0 : w3;
    float4 f0 = *(const float4*)(src + off);
    float4 f1 = *(const float4*)(src + off + 4);
    t[0]=f2bf(sc*f0.x); t[1]=f2bf(sc*f0.y);
    t[2]=f2bf(sc*f0.z); t[3]=f2bf(sc*f0.w);
    t[4]=f2bf(sc*f1.x); t[5]=f2bf(sc*f1.y);
    t[6]=f2bf(sc*f1.z); t[7]=f2bf(sc*f1.w);
  }
  *(bf16x8*)(wbf + (size_t)seg * WM_ + off) = *(bf16x8*)t;
}

// ---------------------------------------------------------------------------
// Projection GEMMs (Q, K'=x*W'^T, V).  128x128 tile over 8 WAVES (512 thr):
// wave tile 32x64 (acc[2][4]), A staged from f32, W bf16 via gload_lds.
// 2-barrier loop, BK=64, XOR-swizzled 32KB LDS, mt-OUTER remap.
// launch_bounds(512,8): 40 VGPR used <= 64 budget -> 4 blocks/CU (128KB LDS).
// Blocks [768, 768+2048): mask bit-pack (2 rows per block).
// Blocks [2816, 2816+256): Wo f32->bf16 conversion (overlaps GEMM compute).
// ---------------------------------------------------------------------------
__global__ __launch_bounds__(512, 8)
void proj_gemm(const float* __restrict__ qx, const float* __restrict__ kx,
               const float* __restrict__ vx,
               const unsigned short* __restrict__ wbf,
               unsigned short* __restrict__ Qb, unsigned short* __restrict__ Kh,
               unsigned short* __restrict__ Vth,
               const int* __restrict__ ma, const int* __restrict__ mb,
               unsigned long long* __restrict__ pk,
               const float* __restrict__ wo, unsigned short* __restrict__ wboOut)
{
  __shared__ unsigned short As[128][64];
  __shared__ unsigned short Ws[128][64];

  const int tid = threadIdx.x, bid = blockIdx.x;

  if (bid >= 2816) {
    // ---- Wo cvt: 256 blocks x 512 thr x 8 elems = 1M elements ----
    const size_t off = ((size_t)(bid - 2816) * 512 + tid) * 8;
    float4 f0 = *(const float4*)(wo + off);
    float4 f1 = *(const float4*)(wo + off + 4);
    union { unsigned u[4]; bf16x8 v; } pu;
    pu.u[0] = cvtpk(f0.x, f0.y); pu.u[1] = cvtpk(f0.z, f0.w);
    pu.u[2] = cvtpk(f1.x, f1.y); pu.u[3] = cvtpk(f1.z, f1.w);
    *(bf16x8*)(wboOut + off) = pu.v;
    return;
  }

  if (bid >= 768) {
    const int row = (bid - 768) * 2 + (tid >> 8);   // 0..4095
    const int w4  = (tid >> 6) & 3, lw = tid & 63;
    const int4 a  = *(const int4*)(ma + (size_t)row*1024 + w4*256 + lw*4);
    const int4 b  = *(const int4*)(mb + (size_t)row*1024 + w4*256 + lw*4);
    const unsigned long long b0 = __ballot((a.x != 0) & (b.x != 0));
    const unsigned long long b1 = __ballot((a.y != 0) & (b.y != 0));
    const unsigned long long b2 = __ballot((a.z != 0) & (b.z != 0));
    const unsigned long long b3 = __ballot((a.w != 0) & (b.w != 0));
    if (lw < 4) {
      const unsigned long long wv =
            ((b0 >> (16*lw)) & 0xFFFFull)
         | (((b1 >> (16*lw)) & 0xFFFFull) << 16)
         | (((b2 >> (16*lw)) & 0xFFFFull) << 32)
         | (((b3 >> (16*lw)) & 0xFFFFull) << 48);
      pk[(size_t)row*16 + w4*4 + lw] = wv;
    }
    return;
  }

  const int xcd = bid & 7, c = bid >> 3;
  const int L = xcd * 96 + c;
  const int which = L >> 8;                   // 0:Q 1:K' 2:V
  const int rem = L & 255;
  const int mt = rem >> 3, nt = rem & 7;      // mt OUTER, nt inner
  const int m0 = mt * 128, n0 = nt * 128;
  const int w = tid >> 6, l = tid & 63;       // w: 0..7
  const int lr = l & 15, lg = l >> 4;
  const int wr = w >> 1, wc = w & 1;          // wave tile 32x64

  const float* Af = (which == 0) ? qx : (which == 1) ? kx : vx;
  const unsigned short* W = wbf + (size_t)which * WM_;

  const f32x4 fzero = {0.f, 0.f, 0.f, 0.f};
  f32x4 acc[2][4];
#pragma unroll
  for (int m = 0; m < 2; m++)
#pragma unroll
    for (int n = 0; n < 4; n++) acc[m][n] = fzero;

  const int r0  = tid >> 3;                   // 0..63
  const int cg  = tid & 7;
  const int aswz = (cg ^ (r0 & 7)) * 8;
  const float* aSrc = Af + (size_t)(m0 + r0) * 1024 + cg * 8;

  const int srow8 = l >> 3;
  const int sg    = ((l & 7) ^ srow8) * 8;
  const unsigned short* wBase = W + (size_t)(n0 + w*16 + srow8) * 1024 + sg;

  const int rc0 = ((lg)     ^ (lr & 7)) * 8;
  const int rc1 = ((4 + lg) ^ (lr & 7)) * 8;

  for (int kk = 0; kk < 1024; kk += 64) {
    float4 fa[2][2];
#pragma unroll
    for (int p = 0; p < 2; ++p) {
      const float* s = aSrc + (size_t)(p*64) * 1024 + kk;
      fa[p][0] = *(const float4*)s;
      fa[p][1] = *(const float4*)(s + 4);
    }
#pragma unroll
    for (int cc = 0; cc < 2; ++cc)
      gload_lds16(wBase + (size_t)cc * 8 * 1024 + kk, &Ws[w*16 + cc*8][0]);
#pragma unroll
    for (int p = 0; p < 2; ++p) {
      union { unsigned u[4]; bf16x8 v; } pu;
      pu.u[0] = cvtpk(fa[p][0].x, fa[p][0].y);
      pu.u[1] = cvtpk(fa[p][0].z, fa[p][0].w);
      pu.u[2] = cvtpk(fa[p][1].x, fa[p][1].y);
      pu.u[3] = cvtpk(fa[p][1].z, fa[p][1].w);
      *(bf16x8*)&As[p*64 + r0][aswz] = pu.v;
    }
    __syncthreads();

#pragma unroll
    for (int ks = 0; ks < 2; ++ks) {
      const int rc = ks ? rc1 : rc0;
      bf16x8 af[2], bfr[4];
#pragma unroll
      for (int m = 0; m < 2; m++) af[m]  = *(const bf16x8*)&As[wr*32 + m*16 + lr][rc];
#pragma unroll
      for (int n = 0; n < 4; n++) bfr[n] = *(const bf16x8*)&Ws[wc*64 + n*16 + lr][rc];
#pragma unroll
      for (int m = 0; m < 2; m++)
#pragma unroll
        for (int n = 0; n < 4; n++)
          acc[m][n] = __builtin_amdgcn_mfma_f32_16x16x32_bf16(af[m], bfr[n], acc[m][n], 0, 0, 0);
    }
    __syncthreads();
  }

  if (which == 2) {
#pragma unroll
    for (int m = 0; m < 2; m++) {
      const int row = m0 + wr*32 + m*16 + lg*4;
      const int b = row >> 10, s = row & 1023;
#pragma unroll
      for (int n = 0; n < 4; n++) {
        const int col = n0 + wc*64 + n*16 + lr;
        const int h = col >> 6, dk = col & 63;
        unsigned short tv[4] = {f2bf(acc[m][n][0]), f2bf(acc[m][n][1]),
                                f2bf(acc[m][n][2]), f2bf(acc[m][n][3])};
        const size_t a = ((size_t)((b*H_ + h)*DK_ + dk)) * S_
                       + (size_t)(s & ~63) + ((((s >> 3) & 7) ^ (dk & 7)) << 3) + (s & 7);
        *(bf16x4*)(Vth + a) = *(bf16x4*)tv;
      }
    }
  } else if (which == 0) {
#pragma unroll
    for (int m = 0; m < 2; m++) {
      const int row = m0 + wr*32 + m*16 + lg*4;
#pragma unroll
      for (int n = 0; n < 4; n++) {
        const int col = n0 + wc*64 + n*16 + lr;
#pragma unroll
        for (int r = 0; r < 4; r++)
          Qb[(size_t)(row + r) * 1024 + col] = f2bf(acc[m][n][r]);
      }
    }
  } else {
#pragma unroll
    for (int m = 0; m < 2; m++) {
      const int row = m0 + wr*32 + m*16 + lg*4;
#pragma unroll
      for (int n = 0; n < 4; n++) {
        const int col = n0 + wc*64 + n*16 + lr;
        const int h = col >> 6, dk = col & 63;
#pragma unroll
        for (int r = 0; r < 4; r++) {
          const int rr = row + r;
          const int b = rr >> 10, s = rr & 1023;
          const size_t a = ((size_t)((b*H_ + h)*S_ + s)) * 64
                         + (((dk >> 3) ^ (s & 7)) << 3) + (dk & 7);
          Kh[a] = f2bf(acc[m][n][r]);
        }
      }
    }
  }
}

// ---------------------------------------------------------------------------
// Final GEMM: out f32 = Xb bf16 * Wo^T.  128x64 tile, BK=64, swizzled LDS.
// ---------------------------------------------------------------------------
__global__ __launch_bounds__(256, 4)
void out_gemm(const unsigned short* __restrict__ A,
              const unsigned short* __restrict__ W, float* __restrict__ C)
{
  __shared__ unsigned short As[128][64];
  __shared__ unsigned short Ws2[64][64];

  const int tid = threadIdx.x, bid = blockIdx.x;
  const int xcd = bid & 7, idx = bid >> 3;
  const int mt = (xcd << 2) | (idx & 3);
  const int nt = idx >> 2;
  const int m0 = mt * 128, n0 = nt * 64;
  const int w = tid >> 6, l = tid & 63;
  const int lr = l & 15, lg = l >> 4;
  const int wr = w >> 1, wc = w & 1;

  const f32x4 fzero = {0.f, 0.f, 0.f, 0.f};
  f32x4 acc[4][2];
#pragma unroll
  for (int m = 0; m < 4; m++)
#pragma unroll
    for (int n = 0; n < 2; n++) acc[m][n] = fzero;

  const int srow8 = l >> 3;
  const int sg    = ((l & 7) ^ srow8) * 8;
  const int rc0 = ((lg)     ^ (lr & 7)) * 8;
  const int rc1 = ((4 + lg) ^ (lr & 7)) * 8;

  const unsigned short* aBase = A + (size_t)(m0 + w*32 + srow8) * 1024 + sg;
  const unsigned short* wBase = W + (size_t)(n0 + w*16 + srow8) * 1024 + sg;

  for (int kk = 0; kk < 1024; kk += 64) {
#pragma unroll
    for (int cc = 0; cc < 4; ++cc)
      gload_lds16(aBase + (size_t)cc * 8 * 1024 + kk, &As[w*32 + cc*8][0]);
#pragma unroll
    for (int cc = 0; cc < 2; ++cc)
      gload_lds16(wBase + (size_t)cc * 8 * 1024 + kk, &Ws2[w*16 + cc*8][0]);
    __syncthreads();

#pragma unroll
    for (int ks = 0; ks < 2; ++ks) {
      const int rc = ks ? rc1 : rc0;
      bf16x8 af[4], bfr[2];
#pragma unroll
      for (int m = 0; m < 4; m++) af[m]  = *(const bf16x8*)&As[wr*64 + m*16 + lr][rc];
#pragma unroll
      for (int n = 0; n < 2; n++) bfr[n] = *(const bf16x8*)&Ws2[wc*32 + n*16 + lr][rc];
#pragma unroll
      for (int m = 0; m < 4; m++)
#pragma unroll
        for (int n = 0; n < 2; n++)
          acc[m][n] = __builtin_amdgcn_mfma_f32_16x16x32_bf16(af[m], bfr[n], acc[m][n], 0, 0, 0);
    }
    __syncthreads();
  }

#pragma unroll
  for (int m = 0; m < 4; m++) {
    const int row = m0 + wr*64 + m*16 + lg*4;
#pragma unroll
    for (int n = 0; n < 2; n++) {
      const int col = n0 + wc*32 + n*16 + lr;
#pragma unroll
      for (int r = 0; r < 4; r++)
        C[(size_t)(row + r) * 1024 + col] = acc[m][n][r];
    }
  }
}

// ---------------------------------------------------------------------------
// Attention: in-block split-K, 8 waves, double-buffered LDS, in-register
// sigmoid.  Mask bit position = 8*sub + hh + 16*(r&3) + 2*(r>>2).
// ---------------------------------------------------------------------------
__global__ __launch_bounds__(512)
void attn_kernel(const unsigned short* __restrict__ Q,
                 const unsigned short* __restrict__ Kh,
                 const unsigned short* __restrict__ Vth,
                 const unsigned long long* __restrict__ mpk,
                 unsigned short* __restrict__ X)
{
  __shared__ unsigned short Ks[2][2][4096];   // [group][buf]
  __shared__ unsigned short Vs[2][2][4096];

  const int tid  = threadIdx.x;
  const int bid0 = blockIdx.x;
  const int bid = ((bid0 & 7) << 6) | (bid0 >> 3);   // XCD swizzle
  const int qt = bid & 7, h = (bid >> 3) & 15, b = bid >> 7;
  const int q0 = qt * 128;
  const int w8 = tid >> 6, lw = tid & 63;
  const int grp = w8 >> 2, qw = w8 & 3;
  const int l31 = lw & 31, hh = lw >> 5, l7 = lw & 7;
  const int bh = b * H_ + h;

  bf16x8 qf[4];
  {
    const unsigned short* qp = Q + ((size_t)(b*S_ + q0 + qw*32 + l31)) * D_ + h*DK_ + hh*8;
#pragma unroll
    for (int ds = 0; ds < 4; ++ds) qf[ds] = *(const bf16x8*)(qp + ds*16);
  }
  const size_t mbase = ((size_t)(b*S_ + q0 + qw*32 + l31)) * 16 + grp*8;

  f32x16 acc0, acc1;
#pragma unroll
  for (int r = 0; r < 16; ++r) { acc0[r] = 0.f; acc1[r] = 0.f; }

  const unsigned short* gp[4];
  unsigned short* lb[4];
  int stp[4];
#pragma unroll
  for (int c = 0; c < 4; ++c) {
    const int e = qw*4 + c;
    const int bu = e >> 3, s = e & 7;
    lb[c] = (bu == 0 ? &Ks[grp][0][0] : &Vs[grp][0][0]) + s*512;
    if (bu == 0) {
      gp[c]  = Kh + (size_t)bh * 65536 + grp*32768 + s*512 + lw*8;
      stp[c] = 4096;
    } else {
      gp[c]  = Vth + ((size_t)(bh*DK_ + s*8 + (lw >> 3))) * S_ + grp*512 + (lw & 7) * 8;
      stp[c] = 64;
    }
  }

#define STAGE(nxt)                                                     \
  {                                                                    \
    _Pragma("unroll")                                                  \
    for (int c = 0; c < 4; ++c) {                                      \
      gload_lds16(gp[c], lb[c] + (nxt)*4096);                          \
      gp[c] += stp[c];                                                 \
    }                                                                  \
  }

  STAGE(0);
  __syncthreads();
  unsigned long long mw = mpk[mbase];
  int cur = 0;

  for (int t = 0; t < 8; ++t) {
    unsigned long long mw_n = 0;
    if (t < 7) { STAGE(cur ^ 1); mw_n = mpk[mbase + t + 1]; }

#pragma unroll
    for (int sub = 0; sub < 2; ++sub) {
      const int rbase = (sub*32 + l31) * 64;
      f32x16 sv;
#pragma unroll
      for (int r = 0; r < 16; ++r) sv[r] = 0.f;
      __builtin_amdgcn_s_setprio(1);
#pragma unroll
      for (int ds = 0; ds < 4; ++ds) {
        const int g = (((ds*2 + hh) ^ l7)) * 8;
        const bf16x8 kf = *(const bf16x8*)&Ks[grp][cur][rbase + g];
        sv = __builtin_amdgcn_mfma_f32_32x32x16_bf16(kf, qf[ds], sv, 0, 0, 0);
      }
      __builtin_amdgcn_s_setprio(0);

      const unsigned long long ams = mw >> (8*sub + hh);
      float p[16];
#pragma unroll
      for (int r = 0; r < 16; ++r) {
        const int cbit = 16*(r & 3) + 2*(r >> 2);
        const float e  = __builtin_amdgcn_exp2f(sv[r]);   // scale pre-folded
        const float pr = __builtin_amdgcn_rcpf(1.0f + e);
        p[r] = ((ams >> cbit) & 1ull) ? pr : 0.f;
      }

      bf16x8 pa[2];
#pragma unroll
      for (int ks = 0; ks < 2; ++ks) {
        const int a0 = ks*8;
        unsigned u0 = cvtpk(p[a0+0], p[a0+1]);
        unsigned u1 = cvtpk(p[a0+2], p[a0+3]);
        unsigned u2 = cvtpk(p[a0+4], p[a0+5]);
        unsigned u3 = cvtpk(p[a0+6], p[a0+7]);
        plswap(u0, u2);
        plswap(u1, u3);
        union { unsigned u[4]; bf16x8 v; } pu;
        pu.u[0] = u0; pu.u[1] = u1; pu.u[2] = u2; pu.u[3] = u3;
        pa[ks] = pu.v;
      }

      __builtin_amdgcn_s_setprio(1);
#pragma unroll
      for (int ks = 0; ks < 2; ++ks) {
        const int g = ((sub*4 + ks*2 + hh) ^ l7) * 8;
        const bf16x8 vb0 = *(const bf16x8*)&Vs[grp][cur][(l31)      * 64 + g];
        const bf16x8 vb1 = *(const bf16x8*)&Vs[grp][cur][(32 + l31) * 64 + g];
        acc0 = __builtin_amdgcn_mfma_f32_32x32x16_bf16(pa[ks], vb0, acc0, 0, 0, 0);
        acc1 = __builtin_amdgcn_mfma_f32_32x32x16_bf16(pa[ks], vb1, acc1, 0, 0, 0);
      }
      __builtin_amdgcn_s_setprio(0);
    }

    if (t < 7) {
      __syncthreads();
      mw = mw_n;
      cur ^= 1;
    }
  }
#undef STAGE

  // ---- split-K combine ----
  __syncthreads();
  float2* cmb = (float2*)&Ks[0][0][0];
  if (grp == 1) {
#pragma unroll
    for (int i = 0; i < 8; ++i)
      cmb[(qw*16 + i)*64 + lw] = make_float2(acc0[2*i], acc0[2*i+1]);
#pragma unroll
    for (int i = 0; i < 8; ++i)
      cmb[(qw*16 + 8 + i)*64 + lw] = make_float2(acc1[2*i], acc1[2*i+1]);
  }
  __syncthreads();
  if (grp == 0) {
#pragma unroll
    for (int i = 0; i < 8; ++i) {
      float2 v = cmb[(qw*16 + i)*64 + lw];
      acc0[2*i] += v.x; acc0[2*i+1] += v.y;
    }
#pragma unroll
    for (int i = 0; i < 8; ++i) {
      float2 v = cmb[(qw*16 + 8 + i)*64 + lw];
      acc1[2*i] += v.x; acc1[2*i+1] += v.y;
    }
#pragma unroll
    for (int r = 0; r < 16; ++r) {
      const int qrow = q0 + qw*32 + (r & 3) + 8*(r >> 2) + 4*hh;
      unsigned short* xp = X + ((size_t)(b*S_ + qrow)) * D_ + h*DK_ + l31;
      xp[0]  = f2bf(acc0[r]);
      xp[32] = f2bf(acc1[r]);
    }
  }
}

// ---------------------------------------------------------------------------
extern "C" void kernel_launch(void* const* d_in, const int* in_sizes, int n_in,
                              void* d_out, int out_size, void* d_ws, size_t ws_size,
                              hipStream_t stream)
{
  const float* query = (const float*)d_in[0];
  const float* key_x = (const float*)d_in[1];
  const float* value = (const float*)d_in[2];
  const int*   mask0 = (const int*)d_in[3];
  const int*   mask1 = (const int*)d_in[4];
  const float* Wq    = (const float*)d_in[5];
  const float* Wk0   = (const float*)d_in[6];
  const float* Wk1   = (const float*)d_in[7];
  const float* Wv    = (const float*)d_in[8];
  const float* Wo    = (const float*)d_in[9];

  unsigned short* ws = (unsigned short*)d_ws;
  unsigned short* wbf = ws;                             // 4 x WM_ (seg3 = Wo)
  unsigned short* Qb  = ws + (size_t)4 * WM_;
  unsigned short* Kh  = Qb  + (size_t)TM_;
  unsigned short* Vth = Kh  + (size_t)TM_;
  unsigned long long* mpk = (unsigned long long*)(Vth + (size_t)TM_);
  unsigned short* Xb = (unsigned short*)(mpk + 65536);

  cvt_w<<<dim3(1536), dim3(256), 0, stream>>>(Wq, Wk0, Wk1, Wv, wbf);

  proj_gemm<<<dim3(768 + 2048 + 256), dim3(512), 0, stream>>>(
      query, key_x, value, wbf, Qb, Kh, Vth, mask0, mask1, mpk,
      Wo, wbf + (size_t)3 * WM_);

  attn_kernel<<<dim3(B_ * H_ * (S_ / 128)), dim3(512), 0, stream>>>(
      Qb, Kh, Vth, mpk, Xb);

  out_gemm<<<dim3(512), dim3(256), 0, stream>>>(Xb, wbf + (size_t)3 * WM_,
                                                (float*)d_out);
}

// Round 22
// 92.611 us; speedup vs baseline: 1.0396x; 1.0396x over previous
//
#include <hip/hip_runtime.h>

#define B_  4
#define S_  1024
#define D_  1024
#define H_  16
#define DK_ 64

typedef __attribute__((ext_vector_type(8)))  short bf16x8;
typedef __attribute__((ext_vector_type(4)))  short bf16x4;
typedef __attribute__((ext_vector_type(4)))  float f32x4;
typedef __attribute__((ext_vector_type(16))) float f32x16;

static __device__ __forceinline__ unsigned short f2bf(float f) {
  union { float f; unsigned u; } v; v.f = f;
  unsigned r = v.u + 0x7FFFu + ((v.u >> 16) & 1u);   // RNE
  return (unsigned short)(r >> 16);
}

static __device__ __forceinline__ unsigned cvtpk(float lo, float hi) {
  unsigned r;
  asm("v_cvt_pk_bf16_f32 %0, %1, %2" : "=v"(r) : "v"(lo), "v"(hi));
  return r;
}
static __device__ __forceinline__ void plswap(unsigned &a, unsigned &b) {
  asm volatile("v_permlane32_swap_b32 %0, %1" : "+v"(a), "+v"(b));
}

typedef __attribute__((address_space(1))) const void gc_t;
typedef __attribute__((address_space(3))) void lds_t;
static __device__ __forceinline__ void gload_lds16(const void* g, void* l) {
  __builtin_amdgcn_global_load_lds((gc_t*)g, (lds_t*)l, 16, 0, 0);
}

#define TM_ (1u << 22)
#define WM_ (1u << 20)

// -0.125 * log2(e): sigmoid(0.125*t) = 1/(1+exp2(CEXP*t)); folded into Wq.
#define CEXP_ (-0.18033688011112042f)

// ---------------------------------------------------------------------------
// cvt_w: weights for proj only (segs 0-2): seg0=CEXP*Wq, seg1=Wk0+0.5*Wk1,
// seg2=Wv.  1536 blocks.  (Wo/seg3 is converted inside proj's tail blocks.)
// ---------------------------------------------------------------------------
__global__ __launch_bounds__(256)
void cvt_w(const float* __restrict__ w0, const float* __restrict__ w1,
           const float* __restrict__ w2, const float* __restrict__ w3,
           unsigned short* __restrict__ wbf)
{
  const size_t u = ((size_t)blockIdx.x * 256 + threadIdx.x) * 8;
  const int seg = (int)(u >> 20);
  const size_t off = u & (WM_ - 1);
  unsigned short t[8];
  if (seg == 1) {               // W' = Wk0 + 0.5*Wk1 (f32, round once)
    float4 a0 = *(const float4*)(w1 + off);
    float4 a1 = *(const float4*)(w1 + off + 4);
    float4 b0 = *(const float4*)(w2 + off);
    float4 b1 = *(const float4*)(w2 + off + 4);
    t[0]=f2bf(a0.x+0.5f*b0.x); t[1]=f2bf(a0.y+0.5f*b0.y);
    t[2]=f2bf(a0.z+0.5f*b0.z); t[3]=f2bf(a0.w+0.5f*b0.w);
    t[4]=f2bf(a1.x+0.5f*b1.x); t[5]=f2bf(a1.y+0.5f*b1.y);
    t[6]=f2bf(a1.z+0.5f*b1.z); t[7]=f2bf(a1.w+0.5f*b1.w);
  } else {
    const float sc = (seg == 0) ? CEXP_ : 1.0f;
    const float* src = (seg == 0) ? w0 : w3;
    float4 f0 = *(const float4*)(src + off);
    float4 f1 = *(const float4*)(src + off + 4);
    t[0]=f2bf(sc*f0.x); t[1]=f2bf(sc*f0.y);
    t[2]=f2bf(sc*f0.z); t[3]=f2bf(sc*f0.w);
    t[4]=f2bf(sc*f1.x); t[5]=f2bf(sc*f1.y);
    t[6]=f2bf(sc*f1.z); t[7]=f2bf(sc*f1.w);
  }
  *(bf16x8*)(wbf + (size_t)seg * WM_ + off) = *(bf16x8*)t;
}

// ---------------------------------------------------------------------------
// Projection GEMMs (Q, K'=x*W'^T, V).  128x128 tile over 8 WAVES (512 thr):
// wave tile 32x64 (acc[2][4]), A staged from f32, W bf16 via gload_lds.
// 2-barrier loop, BK=64, XOR-swizzled 32KB LDS, mt-OUTER remap.
// Blocks [768, 768+2048): mask bit-pack (2 rows per block).
// Blocks [2816, 2816+256): Wo f32->bf16 conversion (overlaps GEMM compute).
// ---------------------------------------------------------------------------
__global__ __launch_bounds__(512, 6)
void proj_gemm(const float* __restrict__ qx, const float* __restrict__ kx,
               const float* __restrict__ vx,
               const unsigned short* __restrict__ wbf,
               unsigned short* __restrict__ Qb, unsigned short* __restrict__ Kh,
               unsigned short* __restrict__ Vth,
               const int* __restrict__ ma, const int* __restrict__ mb,
               unsigned long long* __restrict__ pk,
               const float* __restrict__ wo, unsigned short* __restrict__ wboOut)
{
  __shared__ unsigned short As[128][64];
  __shared__ unsigned short Ws[128][64];

  const int tid = threadIdx.x, bid = blockIdx.x;

  if (bid >= 2816) {
    // ---- Wo cvt: 256 blocks x 512 thr x 8 elems = 1M elements ----
    const size_t off = ((size_t)(bid - 2816) * 512 + tid) * 8;
    float4 f0 = *(const float4*)(wo + off);
    float4 f1 = *(const float4*)(wo + off + 4);
    union { unsigned u[4]; bf16x8 v; } pu;
    pu.u[0] = cvtpk(f0.x, f0.y); pu.u[1] = cvtpk(f0.z, f0.w);
    pu.u[2] = cvtpk(f1.x, f1.y); pu.u[3] = cvtpk(f1.z, f1.w);
    *(bf16x8*)(wboOut + off) = pu.v;
    return;
  }

  if (bid >= 768) {
    const int row = (bid - 768) * 2 + (tid >> 8);   // 0..4095
    const int w4  = (tid >> 6) & 3, lw = tid & 63;
    const int4 a  = *(const int4*)(ma + (size_t)row*1024 + w4*256 + lw*4);
    const int4 b  = *(const int4*)(mb + (size_t)row*1024 + w4*256 + lw*4);
    const unsigned long long b0 = __ballot((a.x != 0) & (b.x != 0));
    const unsigned long long b1 = __ballot((a.y != 0) & (b.y != 0));
    const unsigned long long b2 = __ballot((a.z != 0) & (b.z != 0));
    const unsigned long long b3 = __ballot((a.w != 0) & (b.w != 0));
    if (lw < 4) {
      const unsigned long long wv =
            ((b0 >> (16*lw)) & 0xFFFFull)
         | (((b1 >> (16*lw)) & 0xFFFFull) << 16)
         | (((b2 >> (16*lw)) & 0xFFFFull) << 32)
         | (((b3 >> (16*lw)) & 0xFFFFull) << 48);
      pk[(size_t)row*16 + w4*4 + lw] = wv;
    }
    return;
  }

  const int xcd = bid & 7, c = bid >> 3;
  const int L = xcd * 96 + c;
  const int which = L >> 8;                   // 0:Q 1:K' 2:V
  const int rem = L & 255;
  const int mt = rem >> 3, nt = rem & 7;      // mt OUTER, nt inner
  const int m0 = mt * 128, n0 = nt * 128;
  const int w = tid >> 6, l = tid & 63;       // w: 0..7
  const int lr = l & 15, lg = l >> 4;
  const int wr = w >> 1, wc = w & 1;          // wave tile 32x64

  const float* Af = (which == 0) ? qx : (which == 1) ? kx : vx;
  const unsigned short* W = wbf + (size_t)which * WM_;

  const f32x4 fzero = {0.f, 0.f, 0.f, 0.f};
  f32x4 acc[2][4];
#pragma unroll
  for (int m = 0; m < 2; m++)
#pragma unroll
    for (int n = 0; n < 4; n++) acc[m][n] = fzero;

  const int r0  = tid >> 3;                   // 0..63
  const int cg  = tid & 7;
  const int aswz = (cg ^ (r0 & 7)) * 8;
  const float* aSrc = Af + (size_t)(m0 + r0) * 1024 + cg * 8;

  const int srow8 = l >> 3;
  const int sg    = ((l & 7) ^ srow8) * 8;
  const unsigned short* wBase = W + (size_t)(n0 + w*16 + srow8) * 1024 + sg;

  const int rc0 = ((lg)     ^ (lr & 7)) * 8;
  const int rc1 = ((4 + lg) ^ (lr & 7)) * 8;

  for (int kk = 0; kk < 1024; kk += 64) {
    float4 fa[2][2];
#pragma unroll
    for (int p = 0; p < 2; ++p) {
      const float* s = aSrc + (size_t)(p*64) * 1024 + kk;
      fa[p][0] = *(const float4*)s;
      fa[p][1] = *(const float4*)(s + 4);
    }
#pragma unroll
    for (int cc = 0; cc < 2; ++cc)
      gload_lds16(wBase + (size_t)cc * 8 * 1024 + kk, &Ws[w*16 + cc*8][0]);
#pragma unroll
    for (int p = 0; p < 2; ++p) {
      union { unsigned u[4]; bf16x8 v; } pu;
      pu.u[0] = cvtpk(fa[p][0].x, fa[p][0].y);
      pu.u[1] = cvtpk(fa[p][0].z, fa[p][0].w);
      pu.u[2] = cvtpk(fa[p][1].x, fa[p][1].y);
      pu.u[3] = cvtpk(fa[p][1].z, fa[p][1].w);
      *(bf16x8*)&As[p*64 + r0][aswz] = pu.v;
    }
    __syncthreads();

#pragma unroll
    for (int ks = 0; ks < 2; ++ks) {
      const int rc = ks ? rc1 : rc0;
      bf16x8 af[2], bfr[4];
#pragma unroll
      for (int m = 0; m < 2; m++) af[m]  = *(const bf16x8*)&As[wr*32 + m*16 + lr][rc];
#pragma unroll
      for (int n = 0; n < 4; n++) bfr[n] = *(const bf16x8*)&Ws[wc*64 + n*16 + lr][rc];
#pragma unroll
      for (int m = 0; m < 2; m++)
#pragma unroll
        for (int n = 0; n < 4; n++)
          acc[m][n] = __builtin_amdgcn_mfma_f32_16x16x32_bf16(af[m], bfr[n], acc[m][n], 0, 0, 0);
    }
    __syncthreads();
  }

  if (which == 2) {
#pragma unroll
    for (int m = 0; m < 2; m++) {
      const int row = m0 + wr*32 + m*16 + lg*4;
      const int b = row >> 10, s = row & 1023;
#pragma unroll
      for (int n = 0; n < 4; n++) {
        const int col = n0 + wc*64 + n*16 + lr;
        const int h = col >> 6, dk = col & 63;
        unsigned short tv[4] = {f2bf(acc[m][n][0]), f2bf(acc[m][n][1]),
                                f2bf(acc[m][n][2]), f2bf(acc[m][n][3])};
        const size_t a = ((size_t)((b*H_ + h)*DK_ + dk)) * S_
                       + (size_t)(s & ~63) + ((((s >> 3) & 7) ^ (dk & 7)) << 3) + (s & 7);
        *(bf16x4*)(Vth + a) = *(bf16x4*)tv;
      }
    }
  } else if (which == 0) {
#pragma unroll
    for (int m = 0; m < 2; m++) {
      const int row = m0 + wr*32 + m*16 + lg*4;
#pragma unroll
      for (int n = 0; n < 4; n++) {
        const int col = n0 + wc*64 + n*16 + lr;
#pragma unroll
        for (int r = 0; r < 4; r++)
          Qb[(size_t)(row + r) * 1024 + col] = f2bf(acc[m][n][r]);
      }
    }
  } else {
#pragma unroll
    for (int m = 0; m < 2; m++) {
      const int row = m0 + wr*32 + m*16 + lg*4;
#pragma unroll
      for (int n = 0; n < 4; n++) {
        const int col = n0 + wc*64 + n*16 + lr;
        const int h = col >> 6, dk = col & 63;
#pragma unroll
        for (int r = 0; r < 4; r++) {
          const int rr = row + r;
          const int b = rr >> 10, s = rr & 1023;
          const size_t a = ((size_t)((b*H_ + h)*S_ + s)) * 64
                         + (((dk >> 3) ^ (s & 7)) << 3) + (dk & 7);
          Kh[a] = f2bf(acc[m][n][r]);
        }
      }
    }
  }
}

// ---------------------------------------------------------------------------
// Final GEMM: out f32 = Xb bf16 * Wo^T.  128x64 tile, BK=64, swizzled LDS.
// ---------------------------------------------------------------------------
__global__ __launch_bounds__(256, 4)
void out_gemm(const unsigned short* __restrict__ A,
              const unsigned short* __restrict__ W, float* __restrict__ C)
{
  __shared__ unsigned short As[128][64];
  __shared__ unsigned short Ws2[64][64];

  const int tid = threadIdx.x, bid = blockIdx.x;
  const int xcd = bid & 7, idx = bid >> 3;
  const int mt = (xcd << 2) | (idx & 3);
  const int nt = idx >> 2;
  const int m0 = mt * 128, n0 = nt * 64;
  const int w = tid >> 6, l = tid & 63;
  const int lr = l & 15, lg = l >> 4;
  const int wr = w >> 1, wc = w & 1;

  const f32x4 fzero = {0.f, 0.f, 0.f, 0.f};
  f32x4 acc[4][2];
#pragma unroll
  for (int m = 0; m < 4; m++)
#pragma unroll
    for (int n = 0; n < 2; n++) acc[m][n] = fzero;

  const int srow8 = l >> 3;
  const int sg    = ((l & 7) ^ srow8) * 8;
  const int rc0 = ((lg)     ^ (lr & 7)) * 8;
  const int rc1 = ((4 + lg) ^ (lr & 7)) * 8;

  const unsigned short* aBase = A + (size_t)(m0 + w*32 + srow8) * 1024 + sg;
  const unsigned short* wBase = W + (size_t)(n0 + w*16 + srow8) * 1024 + sg;

  for (int kk = 0; kk < 1024; kk += 64) {
#pragma unroll
    for (int cc = 0; cc < 4; ++cc)
      gload_lds16(aBase + (size_t)cc * 8 * 1024 + kk, &As[w*32 + cc*8][0]);
#pragma unroll
    for (int cc = 0; cc < 2; ++cc)
      gload_lds16(wBase + (size_t)cc * 8 * 1024 + kk, &Ws2[w*16 + cc*8][0]);
    __syncthreads();

#pragma unroll
    for (int ks = 0; ks < 2; ++ks) {
      const int rc = ks ? rc1 : rc0;
      bf16x8 af[4], bfr[2];
#pragma unroll
      for (int m = 0; m < 4; m++) af[m]  = *(const bf16x8*)&As[wr*64 + m*16 + lr][rc];
#pragma unroll
      for (int n = 0; n < 2; n++) bfr[n] = *(const bf16x8*)&Ws2[wc*32 + n*16 + lr][rc];
#pragma unroll
      for (int m = 0; m < 4; m++)
#pragma unroll
        for (int n = 0; n < 2; n++)
          acc[m][n] = __builtin_amdgcn_mfma_f32_16x16x32_bf16(af[m], bfr[n], acc[m][n], 0, 0, 0);
    }
    __syncthreads();
  }

#pragma unroll
  for (int m = 0; m < 4; m++) {
    const int row = m0 + wr*64 + m*16 + lg*4;
#pragma unroll
    for (int n = 0; n < 2; n++) {
      const int col = n0 + wc*32 + n*16 + lr;
#pragma unroll
      for (int r = 0; r < 4; r++)
        C[(size_t)(row + r) * 1024 + col] = acc[m][n][r];
    }
  }
}

// ---------------------------------------------------------------------------
// Attention: in-block split-K, 8 waves, double-buffered LDS, in-register
// sigmoid.  Mask bit position = 8*sub + hh + 16*(r&3) + 2*(r>>2).
// ---------------------------------------------------------------------------
__global__ __launch_bounds__(512)
void attn_kernel(const unsigned short* __restrict__ Q,
                 const unsigned short* __restrict__ Kh,
                 const unsigned short* __restrict__ Vth,
                 const unsigned long long* __restrict__ mpk,
                 unsigned short* __restrict__ X)
{
  __shared__ unsigned short Ks[2][2][4096];   // [group][buf]
  __shared__ unsigned short Vs[2][2][4096];

  const int tid  = threadIdx.x;
  const int bid0 = blockIdx.x;
  const int bid = ((bid0 & 7) << 6) | (bid0 >> 3);   // XCD swizzle
  const int qt = bid & 7, h = (bid >> 3) & 15, b = bid >> 7;
  const int q0 = qt * 128;
  const int w8 = tid >> 6, lw = tid & 63;
  const int grp = w8 >> 2, qw = w8 & 3;
  const int l31 = lw & 31, hh = lw >> 5, l7 = lw & 7;
  const int bh = b * H_ + h;

  bf16x8 qf[4];
  {
    const unsigned short* qp = Q + ((size_t)(b*S_ + q0 + qw*32 + l31)) * D_ + h*DK_ + hh*8;
#pragma unroll
    for (int ds = 0; ds < 4; ++ds) qf[ds] = *(const bf16x8*)(qp + ds*16);
  }
  const size_t mbase = ((size_t)(b*S_ + q0 + qw*32 + l31)) * 16 + grp*8;

  f32x16 acc0, acc1;
#pragma unroll
  for (int r = 0; r < 16; ++r) { acc0[r] = 0.f; acc1[r] = 0.f; }

  const unsigned short* gp[4];
  unsigned short* lb[4];
  int stp[4];
#pragma unroll
  for (int c = 0; c < 4; ++c) {
    const int e = qw*4 + c;
    const int bu = e >> 3, s = e & 7;
    lb[c] = (bu == 0 ? &Ks[grp][0][0] : &Vs[grp][0][0]) + s*512;
    if (bu == 0) {
      gp[c]  = Kh + (size_t)bh * 65536 + grp*32768 + s*512 + lw*8;
      stp[c] = 4096;
    } else {
      gp[c]  = Vth + ((size_t)(bh*DK_ + s*8 + (lw >> 3))) * S_ + grp*512 + (lw & 7) * 8;
      stp[c] = 64;
    }
  }

#define STAGE(nxt)                                                     \
  {                                                                    \
    _Pragma("unroll")                                                  \
    for (int c = 0; c < 4; ++c) {                                      \
      gload_lds16(gp[c], lb[c] + (nxt)*4096);                          \
      gp[c] += stp[c];                                                 \
    }                                                                  \
  }

  STAGE(0);
  __syncthreads();
  unsigned long long mw = mpk[mbase];
  int cur = 0;

  for (int t = 0; t < 8; ++t) {
    unsigned long long mw_n = 0;
    if (t < 7) { STAGE(cur ^ 1); mw_n = mpk[mbase + t + 1]; }

#pragma unroll
    for (int sub = 0; sub < 2; ++sub) {
      const int rbase = (sub*32 + l31) * 64;
      f32x16 sv;
#pragma unroll
      for (int r = 0; r < 16; ++r) sv[r] = 0.f;
      __builtin_amdgcn_s_setprio(1);
#pragma unroll
      for (int ds = 0; ds < 4; ++ds) {
        const int g = (((ds*2 + hh) ^ l7)) * 8;
        const bf16x8 kf = *(const bf16x8*)&Ks[grp][cur][rbase + g];
        sv = __builtin_amdgcn_mfma_f32_32x32x16_bf16(kf, qf[ds], sv, 0, 0, 0);
      }
      __builtin_amdgcn_s_setprio(0);

      const unsigned long long ams = mw >> (8*sub + hh);
      float p[16];
#pragma unroll
      for (int r = 0; r < 16; ++r) {
        const int cbit = 16*(r & 3) + 2*(r >> 2);
        const float e  = __builtin_amdgcn_exp2f(sv[r]);   // scale pre-folded
        const float pr = __builtin_amdgcn_rcpf(1.0f + e);
        p[r] = ((ams >> cbit) & 1ull) ? pr : 0.f;
      }

      bf16x8 pa[2];
#pragma unroll
      for (int ks = 0; ks < 2; ++ks) {
        const int a0 = ks*8;
        unsigned u0 = cvtpk(p[a0+0], p[a0+1]);
        unsigned u1 = cvtpk(p[a0+2], p[a0+3]);
        unsigned u2 = cvtpk(p[a0+4], p[a0+5]);
        unsigned u3 = cvtpk(p[a0+6], p[a0+7]);
        plswap(u0, u2);
        plswap(u1, u3);
        union { unsigned u[4]; bf16x8 v; } pu;
        pu.u[0] = u0; pu.u[1] = u1; pu.u[2] = u2; pu.u[3] = u3;
        pa[ks] = pu.v;
      }

      __builtin_amdgcn_s_setprio(1);
#pragma unroll
      for (int ks = 0; ks < 2; ++ks) {
        const int g = ((sub*4 + ks*2 + hh) ^ l7) * 8;
        const bf16x8 vb0 = *(const bf16x8*)&Vs[grp][cur][(l31)      * 64 + g];
        const bf16x8 vb1 = *(const bf16x8*)&Vs[grp][cur][(32 + l31) * 64 + g];
        acc0 = __builtin_amdgcn_mfma_f32_32x32x16_bf16(pa[ks], vb0, acc0, 0, 0, 0);
        acc1 = __builtin_amdgcn_mfma_f32_32x32x16_bf16(pa[ks], vb1, acc1, 0, 0, 0);
      }
      __builtin_amdgcn_s_setprio(0);
    }

    if (t < 7) {
      __syncthreads();
      mw = mw_n;
      cur ^= 1;
    }
  }
#undef STAGE

  // ---- split-K combine ----
  __syncthreads();
  float2* cmb = (float2*)&Ks[0][0][0];
  if (grp == 1) {
#pragma unroll
    for (int i = 0; i < 8; ++i)
      cmb[(qw*16 + i)*64 + lw] = make_float2(acc0[2*i], acc0[2*i+1]);
#pragma unroll
    for (int i = 0; i < 8; ++i)
      cmb[(qw*16 + 8 + i)*64 + lw] = make_float2(acc1[2*i], acc1[2*i+1]);
  }
  __syncthreads();
  if (grp == 0) {
#pragma unroll
    for (int i = 0; i < 8; ++i) {
      float2 v = cmb[(qw*16 + i)*64 + lw];
      acc0[2*i] += v.x; acc0[2*i+1] += v.y;
    }
#pragma unroll
    for (int i = 0; i < 8; ++i) {
      float2 v = cmb[(qw*16 + 8 + i)*64 + lw];
      acc1[2*i] += v.x; acc1[2*i+1] += v.y;
    }
#pragma unroll
    for (int r = 0; r < 16; ++r) {
      const int qrow = q0 + qw*32 + (r & 3) + 8*(r >> 2) + 4*hh;
      unsigned short* xp = X + ((size_t)(b*S_ + qrow)) * D_ + h*DK_ + l31;
      xp[0]  = f2bf(acc0[r]);
      xp[32] = f2bf(acc1[r]);
    }
  }
}

// ---------------------------------------------------------------------------
extern "C" void kernel_launch(void* const* d_in, const int* in_sizes, int n_in,
                              void* d_out, int out_size, void* d_ws, size_t ws_size,
                              hipStream_t stream)
{
  const float* query = (const float*)d_in[0];
  const float* key_x = (const float*)d_in[1];
  const float* value = (const float*)d_in[2];
  const int*   mask0 = (const int*)d_in[3];
  const int*   mask1 = (const int*)d_in[4];
  const float* Wq    = (const float*)d_in[5];
  const float* Wk0   = (const float*)d_in[6];
  const float* Wk1   = (const float*)d_in[7];
  const float* Wv    = (const float*)d_in[8];
  const float* Wo    = (const float*)d_in[9];

  unsigned short* ws = (unsigned short*)d_ws;
  unsigned short* wbf = ws;                             // 4 x WM_ (seg3 = Wo)
  unsigned short* Qb  = ws + (size_t)4 * WM_;
  unsigned short* Kh  = Qb  + (size_t)TM_;
  unsigned short* Vth = Kh  + (size_t)TM_;
  unsigned long long* mpk = (unsigned long long*)(Vth + (size_t)TM_);
  unsigned short* Xb = (unsigned short*)(mpk + 65536);

  cvt_w<<<dim3(1536), dim3(256), 0, stream>>>(Wq, Wk0, Wk1, Wv, wbf);

  proj_gemm<<<dim3(768 + 2048 + 256), dim3(512), 0, stream>>>(
      query, key_x, value, wbf, Qb, Kh, Vth, mask0, mask1, mpk,
      Wo, wbf + (size_t)3 * WM_);

  attn_kernel<<<dim3(B_ * H_ * (S_ / 128)), dim3(512), 0, stream>>>(
      Qb, Kh, Vth, mpk, Xb);

  out_gemm<<<dim3(512), dim3(256), 0, stream>>>(Xb, wbf + (size_t)3 * WM_,
                                                (float*)d_out);
}